// Round 4
// baseline (3913.108 us; speedup 1.0000x reference)
//
#include <hip/hip_runtime.h>
#include <hip/hip_bf16.h>
#include <math.h>

#define NEGV -1e9f
#define NEGH -5e8f

__device__ __forceinline__ unsigned fkey(float f) {
  unsigned u = __float_as_uint(f);
  return (u & 0x80000000u) ? ~u : (u | 0x80000000u);
}
// 48-bit total-order key: (score desc, original index asc). Unique per candidate.
__device__ __forceinline__ unsigned long long key48(float s, int j) {
  return ((unsigned long long)fkey(s) << 15) | (unsigned long long)(32767 - j);
}
__device__ __forceinline__ float unkey_score(unsigned long long k) {
  unsigned u = (unsigned)(k >> 15);
  return (u & 0x80000000u) ? __uint_as_float(u & 0x7FFFFFFFu)
                           : __uint_as_float(~u);
}

// ------------------------------------------------------------------
// Prep 1: feat [8,512,50,50] -> featP [8,512,52,52] fp32, zero border
// (im2col taps need no predication).
// ------------------------------------------------------------------
__global__ __launch_bounds__(256) void pad_kernel(
    const float* __restrict__ feat, float* __restrict__ featP) {
  int i = blockIdx.x * 256 + threadIdx.x;   // 8*512*2704 exact
  int pp = i % 2704;
  int bc = i / 2704;
  int py = pp / 52, px = pp - py * 52;
  float v = 0.f;
  if (py >= 1 && py <= 50 && px >= 1 && px <= 50)
    v = feat[bc * 2500 + (py - 1) * 50 + (px - 1)];
  featP[i] = v;
}

// ------------------------------------------------------------------
// Prep 2: W1 [oc][cin][tap] -> W1t [tap][cin][oc] (A-tile staging
// becomes coalesced row loads).
// ------------------------------------------------------------------
__global__ __launch_bounds__(256) void wt_kernel(
    const float* __restrict__ W1, float* __restrict__ W1t) {
  int i = blockIdx.x * 256 + threadIdx.x;   // 9*512*512 exact
  int oc = i & 511;
  int rest = i >> 9;
  int cin = rest & 511;
  int tap = rest >> 9;
  W1t[i] = W1[(size_t)oc * 4608 + cin * 9 + tap];
}

// ------------------------------------------------------------------
// Conv 3x3 SAME as fp32 GEMM: C[ch][pix] = sum_k W[ch][k]*im2col[k][pix].
// K-order: tap-major (tap*512 + cin), 144 steps of BK=32.
// Tile 128(ch) x 64(pix), 256 threads, 8x4 micro-tile, single 24KB LDS
// buffer, 2-phase reg-staged pipeline (loads for s+1 overlap compute(s)).
// ------------------------------------------------------------------
__global__ __launch_bounds__(256) void conv_opt_kernel(
    const float* __restrict__ featP, const float* __restrict__ W1t,
    const float* __restrict__ b1, float* __restrict__ out) {
  __shared__ float As[32][128];   // [k][ch]
  __shared__ float Bs[32][64];    // [k][pix]
  const int tid = threadIdx.x;
  const int b  = blockIdx.z;
  const int m0 = blockIdx.y * 128;
  const int n0 = blockIdx.x * 64;
  const int wv = tid >> 6, ln = tid & 63;

  // B staging map: lane -> pixel, wave -> 8-k slice
  int p = n0 + ln; if (p > 2499) p = 2499;
  const int py = p / 50;
  const int ppadc = (py + 1) * 52 + (p - py * 50 + 1);
  const float* featb = featP + (size_t)b * 512 * 2704;

  // A staging map: thread -> (k row, 16-ch chunk)
  const int ak = tid >> 3;          // 0..31
  const int ac = (tid & 7) * 16;    // 0..112

  // compute map: 16x16 thread grid, 8 ch x 4 pix micro-tile
  const int tn = tid & 15, tm = tid >> 4;

  float acc[8][4];
  #pragma unroll
  for (int i = 0; i < 8; ++i)
    #pragma unroll
    for (int j = 0; j < 4; ++j) acc[i][j] = 0.f;

  float4 rA[4];
  float  rB[8];

  auto loadA = [&](int s) {
    // row index (tap*512 + cinb*32 + ak) == s*32 + ak
    const float* src = W1t + ((size_t)s * 32 + ak) * 512 + m0 + ac;
    #pragma unroll
    for (int j = 0; j < 4; ++j) rA[j] = *(const float4*)(src + j * 4);
  };
  auto loadB = [&](int s) {
    int tap = s >> 4;
    int dy = tap / 3, dx = tap - dy * 3;
    const float* basep = featb + (size_t)(((s & 15) << 5) + wv * 8) * 2704
                       + ppadc + (dy - 1) * 52 + (dx - 1);
    #pragma unroll
    for (int q = 0; q < 8; ++q) rB[q] = basep[(size_t)q * 2704];
  };
  auto writeS = [&]() {
    #pragma unroll
    for (int j = 0; j < 4; ++j) *(float4*)&As[ak][ac + j * 4] = rA[j];
    #pragma unroll
    for (int q = 0; q < 8; ++q) Bs[wv * 8 + q][ln] = rB[q];
  };
  auto compute = [&]() {
    for (int k = 0; k < 32; ++k) {
      float a[8], bb[4];
      *(float4*)&a[0]  = *(const float4*)&As[k][tm * 8];
      *(float4*)&a[4]  = *(const float4*)&As[k][tm * 8 + 4];
      *(float4*)&bb[0] = *(const float4*)&Bs[k][tn * 4];
      #pragma unroll
      for (int i = 0; i < 8; ++i)
        #pragma unroll
        for (int j = 0; j < 4; ++j)
          acc[i][j] = fmaf(a[i], bb[j], acc[i][j]);
    }
  };

  loadA(0); loadB(0);
  writeS();
  __syncthreads();
  #pragma unroll 1
  for (int s = 0; s < 144; ++s) {
    if (s + 1 < 144) { loadA(s + 1); loadB(s + 1); }  // in flight over compute
    compute();
    __syncthreads();                                   // all waves done reading
    if (s + 1 < 144) { writeS(); __syncthreads(); }    // buffer ready
  }

  float bias[8];
  *(float4*)&bias[0] = *(const float4*)&b1[m0 + tm * 8];
  *(float4*)&bias[4] = *(const float4*)&b1[m0 + tm * 8 + 4];
  #pragma unroll
  for (int j = 0; j < 4; ++j) {
    int pix = n0 + tn * 4 + j;
    if (pix < 2500) {
      float* op = out + (size_t)(b * 2500 + pix) * 512 + m0 + tm * 8;
      float4 v0, v1;
      v0.x = fmaxf(acc[0][j] + bias[0], 0.f); v0.y = fmaxf(acc[1][j] + bias[1], 0.f);
      v0.z = fmaxf(acc[2][j] + bias[2], 0.f); v0.w = fmaxf(acc[3][j] + bias[3], 0.f);
      v1.x = fmaxf(acc[4][j] + bias[4], 0.f); v1.y = fmaxf(acc[5][j] + bias[5], 0.f);
      v1.z = fmaxf(acc[6][j] + bias[6], 0.f); v1.w = fmaxf(acc[7][j] + bias[7], 0.f);
      *(float4*)op       = v0;
      *(float4*)(op + 4) = v1;
    }
  }
}

// ------------------------------------------------------------------
// fp32 fallback conv (round-2, known-good) for small-ws case
// ------------------------------------------------------------------
__global__ __launch_bounds__(256) void conv3x3_kernel(
    const float* __restrict__ feat, const float* __restrict__ W1,
    const float* __restrict__ b1, float* __restrict__ out) {
  __shared__ float As[36][132];
  __shared__ float Bs[36][128];
  const int tid = threadIdx.x;
  const int b  = blockIdx.z;
  const int m0 = blockIdx.y * 128;
  const int n0 = blockIdx.x * 128;
  const int tn = tid & 15, tm = tid >> 4;
  const int lm = tid & 127;
  const int kh = tid >> 7;
  const int ng = n0 + lm;
  const int yy = ng / 50;
  const int xx = ng - yy * 50;
  const bool npix_ok = (ng < 2500);
  const float* featb = feat + b * (512 * 2500);
  const float* arow  = W1 + (m0 + lm) * 4608;
  float acc[8][8];
  #pragma unroll
  for (int i = 0; i < 8; ++i)
    #pragma unroll
    for (int j = 0; j < 8; ++j) acc[i][j] = 0.f;
  for (int kc = 0; kc < 4608; kc += 36) {
    #pragma unroll
    for (int i = 0; i < 18; ++i) { int k = i * 2 + kh; As[k][lm] = arow[kc + k]; }
    #pragma unroll
    for (int i = 0; i < 18; ++i) {
      int k = i * 2 + kh;
      int kg = kc + k;
      int cin = kg / 9;
      int off = kg - cin * 9;
      int dy = off / 3;
      int dx = off - dy * 3;
      int iy = yy + dy - 1, ix = xx + dx - 1;
      float v = 0.f;
      if (npix_ok && (unsigned)iy < 50u && (unsigned)ix < 50u)
        v = featb[cin * 2500 + iy * 50 + ix];
      Bs[k][lm] = v;
    }
    __syncthreads();
    for (int k = 0; k < 36; ++k) {
      float a[8], bb[8];
      *(float4*)&a[0]  = *(const float4*)&As[k][tm * 8];
      *(float4*)&a[4]  = *(const float4*)&As[k][tm * 8 + 4];
      *(float4*)&bb[0] = *(const float4*)&Bs[k][tn * 8];
      *(float4*)&bb[4] = *(const float4*)&Bs[k][tn * 8 + 4];
      #pragma unroll
      for (int i = 0; i < 8; ++i)
        #pragma unroll
        for (int j = 0; j < 8; ++j)
          acc[i][j] = fmaf(a[i], bb[j], acc[i][j]);
    }
    __syncthreads();
  }
  float bias[8];
  *(float4*)&bias[0] = *(const float4*)&b1[m0 + tm * 8];
  *(float4*)&bias[4] = *(const float4*)&b1[m0 + tm * 8 + 4];
  for (int j = 0; j < 8; ++j) {
    int n = n0 + tn * 8 + j;
    if (n >= 2500) break;
    float* op = out + (size_t)(b * 2500 + n) * 512 + m0 + tm * 8;
    float4 v0, v1;
    v0.x = fmaxf(acc[0][j] + bias[0], 0.f); v0.y = fmaxf(acc[1][j] + bias[1], 0.f);
    v0.z = fmaxf(acc[2][j] + bias[2], 0.f); v0.w = fmaxf(acc[3][j] + bias[3], 0.f);
    v1.x = fmaxf(acc[4][j] + bias[4], 0.f); v1.y = fmaxf(acc[5][j] + bias[5], 0.f);
    v1.z = fmaxf(acc[6][j] + bias[6], 0.f); v1.w = fmaxf(acc[7][j] + bias[7], 0.f);
    *(float4*)op       = v0;
    *(float4*)(op + 4) = v1;
  }
}

// ------------------------------------------------------------------
// Heads (unchanged, verified in round 2)
// ------------------------------------------------------------------
__global__ __launch_bounds__(256) void heads_kernel(
    const float* __restrict__ conv1,
    const float* __restrict__ Wreg, const float* __restrict__ breg,
    const float* __restrict__ Wcls, const float* __restrict__ bcls,
    float* __restrict__ boxes, float* __restrict__ scores) {
  __shared__ float v[4][512];
  __shared__ float o54[4][56];
  const int tid = threadIdx.x;
  const int w = tid >> 6, lane = tid & 63;
  const int pix = blockIdx.x * 4 + w;
  const int b = pix / 2500;
  const int n = pix - b * 2500;
  const int y = n / 50, x = n - y * 50;
  const float* src = conv1 + (size_t)pix * 512;
  *(float4*)&v[w][lane * 8]     = *(const float4*)&src[lane * 8];
  *(float4*)&v[w][lane * 8 + 4] = *(const float4*)&src[lane * 8 + 4];
  __syncthreads();
  if (lane < 54) {
    const float* wrow = (lane < 36) ? (Wreg + lane * 512) : (Wcls + (lane - 36) * 512);
    float s0 = 0.f, s1 = 0.f, s2 = 0.f, s3 = 0.f;
    for (int c = 0; c < 512; c += 4) {
      float4 wv = *(const float4*)&wrow[c];
      float4 vv = *(const float4*)&v[w][c];
      s0 = fmaf(vv.x, wv.x, s0);
      s1 = fmaf(vv.y, wv.y, s1);
      s2 = fmaf(vv.z, wv.z, s2);
      s3 = fmaf(vv.w, wv.w, s3);
    }
    o54[w][lane] = (s0 + s1) + (s2 + s3) + (lane < 36 ? breg[lane] : bcls[lane - 36]);
  }
  __syncthreads();
  if (lane < 9) {
    const int a = lane;
    float d0 = o54[w][a * 4 + 0], d1 = o54[w][a * 4 + 1];
    float d2 = o54[w][a * 4 + 2], d3 = o54[w][a * 4 + 3];
    float sc0 = o54[w][36 + a * 2], sc1 = o54[w][36 + a * 2 + 1];
    float mx = fmaxf(sc0, sc1);
    float e0 = expf(sc0 - mx), e1 = expf(sc1 - mx);
    float fg = e1 / (e0 + e1);
    const int ri = a / 3;
    const int si = a - ri * 3;
    float sv = (si == 0) ? 8.f : (si == 1 ? 16.f : 32.f);
    float sqr_r  = (ri == 0) ? 0.70710678f : (ri == 1 ? 1.f : 1.41421356f);
    float sqr_ir = (ri == 0) ? 1.41421356f : (ri == 1 ? 1.f : 0.70710678f);
    float hh = 16.f * sv * sqr_r;
    float ww = 16.f * sv * sqr_ir;
    float acy = 16.f * (float)(y + 1) - 25.f;
    float acx = 16.f * (float)(x + 1) - 25.f;
    float ay1 = acy - 0.5f * hh, ay2 = acy + 0.5f * hh;
    float ax1 = acx - 0.5f * ww, ax2 = acx + 0.5f * ww;
    float ah = ay2 - ay1, aw = ax2 - ax1;
    float cy0 = ay1 + 0.5f * ah, cx0 = ax1 + 0.5f * aw;
    float cy = d0 * ah + cy0, cx = d1 * aw + cx0;
    float bh = expf(d2) * ah, bw = expf(d3) * aw;
    float y1 = cy - 0.5f * bh, x1 = cx - 0.5f * bw;
    float y2 = cy + 0.5f * bh, x2 = cx + 0.5f * bw;
    y1 = fminf(fmaxf(y1, 0.f), 800.f); y2 = fminf(fmaxf(y2, 0.f), 800.f);
    x1 = fminf(fmaxf(x1, 0.f), 800.f); x2 = fminf(fmaxf(x2, 0.f), 800.f);
    bool ok = ((y2 - y1) >= 16.f) && ((x2 - x1) >= 16.f);
    int gi = b * 22500 + n * 9 + a;
    ((float4*)boxes)[gi] = make_float4(y1, x1, y2, x2);
    scores[gi] = (ok && fg == fg) ? fg : NEGV;
  }
}

// ------------------------------------------------------------------
// Top-6000 radix select on unique 48-bit keys (unchanged, verified)
// ------------------------------------------------------------------
__global__ __launch_bounds__(256) void topk_kernel(
    const float* __restrict__ scores, const float* __restrict__ boxes,
    float* __restrict__ tsc, float* __restrict__ tbx, int* __restrict__ tidx) {
  const int b = blockIdx.x, tid = threadIdx.x;
  __shared__ unsigned hist[256];
  __shared__ unsigned long long sh_pref;
  __shared__ unsigned sh_rem, sh_cnt;
  const float* sc = scores + b * 22500;
  if (tid == 0) { sh_pref = 0ull; sh_rem = 6000u; }
  __syncthreads();
  for (int pass = 0; pass < 6; ++pass) {
    const int shift = 40 - pass * 8;
    hist[tid] = 0u;
    __syncthreads();
    const unsigned long long pref = sh_pref;
    for (int j = tid; j < 22500; j += 256) {
      unsigned long long key = key48(sc[j], j);
      if ((key >> (shift + 8)) == pref)
        atomicAdd(&hist[(unsigned)(key >> shift) & 255u], 1u);
    }
    __syncthreads();
    if (tid == 0) {
      unsigned rem = sh_rem;
      unsigned c = 0; int sel = 0;
      for (int bin = 255; bin >= 0; --bin) {
        unsigned nc = c + hist[bin];
        if (nc >= rem) { sel = bin; break; }
        c = nc;
      }
      sh_rem = rem - c;
      sh_pref = (sh_pref << 8) | (unsigned long long)sel;
    }
    __syncthreads();
  }
  const unsigned long long T = sh_pref;
  if (tid == 0) sh_cnt = 0u;
  __syncthreads();
  const float4* bx4 = (const float4*)boxes;
  float4* tb4 = (float4*)tbx;
  for (int j = tid; j < 22500; j += 256) {
    unsigned long long key = key48(sc[j], j);
    if (key >= T) {
      unsigned slot = atomicAdd(&sh_cnt, 1u);
      if (slot < 6000u) {
        tsc[b * 6000 + slot] = sc[j];
        tidx[b * 6000 + slot] = j;
        tb4[b * 6000 + slot] = bx4[b * 22500 + j];
      }
    }
  }
}

// ------------------------------------------------------------------
// Greedy NMS: keys in LDS, candidate boxes+areas in registers.
// ------------------------------------------------------------------
__global__ __launch_bounds__(512) void nms_kernel(
    const float* __restrict__ tsc, const float* __restrict__ tbx,
    const int* __restrict__ tidx, float* __restrict__ out) {
  const int b = blockIdx.x, tid = threadIdx.x;
  __shared__ unsigned long long kk[6000];
  __shared__ unsigned long long wk[8];
  __shared__ int wslot[8];
  __shared__ float cur_s, cur_y1, cur_x1, cur_y2, cur_x2, cur_a;
  __shared__ int cur_slot;
  const float4* boxes = (const float4*)tbx + (size_t)b * 6000;
  const float* scs = tsc + b * 6000;
  const int* idxs = tidx + b * 6000;
  float4 bx[12]; float arr[12];
  #pragma unroll
  for (int i = 0; i < 12; ++i) {
    int j = tid + i * 512;
    if (j < 6000) {
      bx[i] = boxes[j];
      arr[i] = (bx[i].z - bx[i].x) * (bx[i].w - bx[i].y);
      kk[j] = key48(scs[j], idxs[j]);
    }
  }
  __syncthreads();

  unsigned long long bk = 0ull; int bs = 0;
  #pragma unroll
  for (int i = 0; i < 12; ++i) {
    int j = tid + i * 512;
    if (j < 6000) { unsigned long long k = kk[j]; if (k > bk) { bk = k; bs = j; } }
  }
  #pragma unroll
  for (int off = 32; off > 0; off >>= 1) {
    unsigned long long ok_ = __shfl_down(bk, off);
    int os = __shfl_down(bs, off);
    if (ok_ > bk) { bk = ok_; bs = os; }
  }
  if ((tid & 63) == 0) { wk[tid >> 6] = bk; wslot[tid >> 6] = bs; }
  __syncthreads();
  if (tid == 0) {
    unsigned long long v = wk[0]; int s = wslot[0];
    for (int k2 = 1; k2 < 8; ++k2)
      if (wk[k2] > v) { v = wk[k2]; s = wslot[k2]; }
    float4 bb = boxes[s];
    cur_s = unkey_score(v); cur_slot = s;
    cur_y1 = bb.x; cur_x1 = bb.y; cur_y2 = bb.z; cur_x2 = bb.w;
    cur_a = (bb.z - bb.x) * (bb.w - bb.y);
  }
  __syncthreads();

  float* rois = out;            // [8][300][5]
  float* rsc  = out + 12000;    // [8][300]
  for (int t = 0; t < 300; ++t) {
    const float cs = cur_s, cy1 = cur_y1, cx1 = cur_x1, cy2 = cur_y2, cx2 = cur_x2, ca = cur_a;
    const int ci = cur_slot;
    if (!(cs > NEGH)) {
      for (int r = t + tid; r < 300; r += 512) {
        float* rp = rois + (size_t)(b * 300 + r) * 5;
        rp[0] = 0.f; rp[1] = 0.f; rp[2] = 0.f; rp[3] = 0.f; rp[4] = 0.f;
        rsc[b * 300 + r] = 0.f;
      }
      break;
    }
    bk = 0ull; bs = 0;
    #pragma unroll
    for (int i = 0; i < 12; ++i) {
      int j = tid + i * 512;
      if (j < 6000) {
        unsigned long long k = kk[j];
        if (k != 0ull) {
          if (j == ci) { kk[j] = 0ull; k = 0ull; }
          else {
            float yy1 = fmaxf(cy1, bx[i].x), xx1 = fmaxf(cx1, bx[i].y);
            float yy2 = fminf(cy2, bx[i].z), xx2 = fminf(cx2, bx[i].w);
            float inter = fmaxf(yy2 - yy1, 0.f) * fmaxf(xx2 - xx1, 0.f);
            float iou = inter / (((ca + arr[i]) - inter) + 1e-9f);
            if (iou > 0.7f) { kk[j] = 0ull; k = 0ull; }
          }
        }
        if (k > bk) { bk = k; bs = j; }
      }
    }
    #pragma unroll
    for (int off = 32; off > 0; off >>= 1) {
      unsigned long long ok_ = __shfl_down(bk, off);
      int os = __shfl_down(bs, off);
      if (ok_ > bk) { bk = ok_; bs = os; }
    }
    if ((tid & 63) == 0) { wk[tid >> 6] = bk; wslot[tid >> 6] = bs; }
    __syncthreads();
    if (tid == 0) {
      float* rp = rois + (size_t)(b * 300 + t) * 5;
      rp[0] = (float)b; rp[1] = cy1; rp[2] = cx1; rp[3] = cy2; rp[4] = cx2;
      rsc[b * 300 + t] = cs;
      unsigned long long v = wk[0]; int s = wslot[0];
      for (int k2 = 1; k2 < 8; ++k2)
        if (wk[k2] > v) { v = wk[k2]; s = wslot[k2]; }
      float4 bb = boxes[s];
      cur_s = unkey_score(v); cur_slot = s;
      cur_y1 = bb.x; cur_x1 = bb.y; cur_y2 = bb.z; cur_x2 = bb.w;
      cur_a = (bb.z - bb.x) * (bb.w - bb.y);
    }
    __syncthreads();
  }
}

// ------------------------------------------------------------------
extern "C" void kernel_launch(void* const* d_in, const int* in_sizes, int n_in,
                              void* d_out, int out_size, void* d_ws, size_t ws_size,
                              hipStream_t stream) {
  const float* feat = (const float*)d_in[0];
  const float* W1   = (const float*)d_in[1];
  const float* b1   = (const float*)d_in[2];
  const float* Wreg = (const float*)d_in[3];
  const float* breg = (const float*)d_in[4];
  const float* Wcls = (const float*)d_in[5];
  const float* bcls = (const float*)d_in[6];
  float* out = (float*)d_out;
  float* ws  = (float*)d_ws;

  // Opt path: featP 11,075,584 f | W1t 2,359,296 f | conv1 10,240,000 f
  //           = 94,699,520 B.  Post-conv buffers alias featP (dead then);
  //           every replay rewrites featP/W1t first -> graph-safe.
  const size_t NEED_OPT = 94699520ull;
  if (ws_size >= NEED_OPT) {
    float* featP = ws;
    float* W1t   = ws + 11075584;
    float* conv1 = ws + 13434880;
    float* boxes  = ws;             // alias featP region (post-conv lifetime)
    float* scores = ws + 720000;
    float* tbx    = ws + 900000;
    float* tsc    = ws + 1092000;
    int*   tidx   = (int*)(ws + 1140000);

    pad_kernel<<<43264, 256, 0, stream>>>(feat, featP);
    wt_kernel<<<9216, 256, 0, stream>>>(W1, W1t);
    conv_opt_kernel<<<dim3(40, 4, 8), 256, 0, stream>>>(featP, W1t, b1, conv1);
    heads_kernel<<<5000, 256, 0, stream>>>(conv1, Wreg, breg, Wcls, bcls, boxes, scores);
    topk_kernel<<<8, 256, 0, stream>>>(scores, boxes, tsc, tbx, tidx);
    nms_kernel<<<8, 512, 0, stream>>>(tsc, tbx, tidx, out);
  } else if (ws_size >= 45712000ull) {
    // round-2 fallback
    float* conv1  = ws;
    float* boxes  = ws + 10240000;
    float* scores = ws + 10960000;
    float* tbx    = ws + 11140000;
    float* tsc    = ws + 11332000;
    int*   tidx   = (int*)(ws + 11380000);
    conv3x3_kernel<<<dim3(20, 4, 8), 256, 0, stream>>>(feat, W1, b1, conv1);
    heads_kernel<<<5000, 256, 0, stream>>>(conv1, Wreg, breg, Wcls, bcls, boxes, scores);
    topk_kernel<<<8, 256, 0, stream>>>(scores, boxes, tsc, tbx, tidx);
    nms_kernel<<<8, 512, 0, stream>>>(tsc, tbx, tidx, out);
  }
}

// Round 5
// 2084.955 us; speedup vs baseline: 1.8768x; 1.8768x over previous
//
#include <hip/hip_runtime.h>
#include <hip/hip_bf16.h>
#include <math.h>

#define NEGV -1e9f
#define NEGH -5e8f
#define GUARD_TOL 0.02f

typedef __attribute__((ext_vector_type(8))) short short8;
typedef __attribute__((ext_vector_type(4))) float f32x4;

__device__ __forceinline__ unsigned fkey(float f) {
  unsigned u = __float_as_uint(f);
  return (u & 0x80000000u) ? ~u : (u | 0x80000000u);
}
__device__ __forceinline__ unsigned long long key48(float s, int j) {
  return ((unsigned long long)fkey(s) << 15) | (unsigned long long)(32767 - j);
}
__device__ __forceinline__ float unkey_score(unsigned long long k) {
  unsigned u = (unsigned)(k >> 15);
  return (u & 0x80000000u) ? __uint_as_float(u & 0x7FFFFFFFu)
                           : __uint_as_float(~u);
}
__device__ __forceinline__ unsigned short bf16_rne(float v) {
  unsigned u = __float_as_uint(v);
  unsigned r = u + 0x7FFFu + ((u >> 16) & 1u);
  return (unsigned short)(r >> 16);
}
__device__ __forceinline__ float bf16_f(unsigned short h) {
  return __uint_as_float(((unsigned)h) << 16);
}

#if defined(__has_builtin)
#if __has_builtin(__builtin_amdgcn_global_load_lds)
#define HAS_GLL 1
#endif
#endif

__device__ __forceinline__ void stage16(const char* gsrc_lane, char* ldsbase, int ln) {
#ifdef HAS_GLL
  typedef unsigned int __attribute__((address_space(1))) gu32;
  typedef unsigned int __attribute__((address_space(3))) lu32;
  __builtin_amdgcn_global_load_lds((const gu32*)gsrc_lane, (lu32*)ldsbase, 16, 0, 0);
#else
  *(uint4*)(ldsbase + ln * 16) = *(const uint4*)gsrc_lane;
#endif
}

// ==================================================================
// Shared tile layout (8 KB: 128 rows x 32 k, bf16):
//   byte(row,k) = (row>>1)*128 + ((((row&1)<<6) + 2k) ^ (((row>>1)&7)<<4))
// 16B fragment reads are 2-way conflicted; b64 writes ~4-way.
// ==================================================================

// ------------------------------------------------------------------
// Pack W1 -> LDS-ready images: [ct=4][s=144][plane hi/mid/lo][8KB].
// K-order kappa = s*32+kk = tap*512+cin. Also resets guard maxd.
// ------------------------------------------------------------------
__global__ __launch_bounds__(256) void w1pack_kernel(
    const float* __restrict__ W1, unsigned* __restrict__ W1pack,
    unsigned* __restrict__ maxd) {
  if (blockIdx.x == 0 && threadIdx.x == 0) *maxd = 0u;
  int d = blockIdx.x * 256 + threadIdx.x;        // 13824*256 = 3,538,944 exact
  int dw = d & 2047;
  int rest = d >> 11;
  int plane = rest % 3;
  int rest2 = rest / 3;
  int s  = rest2 % 144;
  int ct = rest2 / 144;
  int tb = dw * 4;
  int R   = tb >> 7;                 // row-pair
  int val = (tb & 127) ^ ((R & 7) << 4);
  int row = R * 2 + (val >> 6);
  int k   = (val & 63) >> 1;         // shorts k, k+1
  int tap = s >> 4;
  int cin = ((s & 15) << 5) + k;
  const float* wr = W1 + ((size_t)(ct * 128 + row) * 512 + cin) * 9 + tap;
  float w0 = wr[0];
  float w1 = wr[9];                  // cin+1, same tap
  unsigned short o0, o1;
  #pragma unroll
  for (int rep = 0; rep < 1; ++rep) {
    float v0 = w0, v1 = w1;
    unsigned short h0 = bf16_rne(v0), h1 = bf16_rne(v1);
    float r0 = v0 - bf16_f(h0), r1 = v1 - bf16_f(h1);
    unsigned short m0 = bf16_rne(r0), m1 = bf16_rne(r1);
    float q0 = r0 - bf16_f(m0), q1 = r1 - bf16_f(m1);
    unsigned short l0 = bf16_rne(q0), l1 = bf16_rne(q1);
    o0 = (plane == 0) ? h0 : (plane == 1 ? m0 : l0);
    o1 = (plane == 0) ? h1 : (plane == 1 ? m1 : l1);
  }
  W1pack[d] = (unsigned)o0 | ((unsigned)o1 << 16);
}

// ------------------------------------------------------------------
// Conv 3x3 as split-3 bf16 MFMA GEMM (fp32-grade: 6 products).
// Tile 128ch x 128pix, BK=32, 4 waves (2x2 of 64x64), 48KB LDS.
// ------------------------------------------------------------------
__global__ __launch_bounds__(256) void conv_mfma_kernel(
    const float* __restrict__ feat, const char* __restrict__ W1pack,
    const float* __restrict__ b1, float* __restrict__ conv1) {
  __shared__ char smem[49152];       // A planes 3x8K | B planes 3x8K
  const int tid = threadIdx.x;
  const int b  = blockIdx.z;
  const int ct = blockIdx.y;
  const int n0 = blockIdx.x * 128;
  const int wv = tid >> 6, ln = tid & 63;

  // B staging: thread -> (pixel, half of k)
  const int spix = tid & 127;
  const int kh   = tid >> 7;                       // 0/1 -> k 0..15 / 16..31
  int p = n0 + spix; if (p > 2499) p = 2499;
  const int pyy = p / 50;
  const int pxx = p - pyy * 50;
  const float* featb = feat + (size_t)b * 512 * 2500;
  const char* wsrc = W1pack + (size_t)ct * 144 * 24576;

  // compute mapping
  const int wch0  = (wv >> 1) * 64;
  const int wpix0 = (wv & 1) * 64;
  const int lrow = ln & 15, lg = ln >> 4;

  f32x4 acc[4][4];
  #pragma unroll
  for (int i = 0; i < 4; ++i)
    #pragma unroll
    for (int j = 0; j < 4; ++j) acc[i][j] = (f32x4)0.f;

  float u[16];

  auto loadFeat = [&](int s) {
    int tap = s >> 4;
    int dy = tap / 3, dx = tap - dy * 3;
    int iy = pyy + dy - 1, ix = pxx + dx - 1;
    bool ok = ((unsigned)iy < 50u) && ((unsigned)ix < 50u);
    int cinb = ((s & 15) << 5) + kh * 16;
    const float* base = featb + (size_t)cinb * 2500 + iy * 50 + ix;
    #pragma unroll
    for (int i = 0; i < 16; ++i) u[i] = ok ? base[(size_t)i * 2500] : 0.f;
  };
  auto issueA = [&](int s) {
    const char* src = wsrc + (size_t)s * 24576;
    char* lbase = smem + (tid >> 6) * 1024;        // wave-uniform
    #pragma unroll
    for (int c = 0; c < 6; ++c)
      stage16(src + c * 4096 + tid * 16, lbase + c * 4096, ln);
  };
  auto writeB = [&]() {
    unsigned short h[16], m[16], l[16];
    #pragma unroll
    for (int i = 0; i < 16; ++i) {
      float v = u[i];
      h[i] = bf16_rne(v);
      float r1 = v - bf16_f(h[i]);
      m[i] = bf16_rne(r1);
      float r2 = r1 - bf16_f(m[i]);
      l[i] = bf16_rne(r2);
    }
    const int r = spix >> 1;
    const int swz = (r & 7) << 4;
    char* rowb = smem + 24576 + r * 128;
    #pragma unroll
    for (int pl = 0; pl < 3; ++pl) {
      const unsigned short* sp = (pl == 0) ? h : (pl == 1 ? m : l);
      char* pb = rowb + pl * 8192;
      #pragma unroll
      for (int q = 0; q < 4; ++q) {
        int pre = ((spix & 1) << 6) + kh * 32 + q * 8;
        uint2 w;
        w.x = (unsigned)sp[q*4]   | ((unsigned)sp[q*4+1] << 16);
        w.y = (unsigned)sp[q*4+2] | ((unsigned)sp[q*4+3] << 16);
        *(uint2*)(pb + (pre ^ swz)) = w;
      }
    }
  };
  auto rdFrag = [&](const char* base, int row) -> short8 {
    int byte = (row >> 1) * 128 +
               ((((row & 1) << 6) + (lg << 4)) ^ (((row >> 1) & 7) << 4));
    return *(const short8*)(base + byte);
  };

  loadFeat(0);
  #pragma unroll 1
  for (int s = 0; s < 144; ++s) {
    __syncthreads();                 // previous compute done with LDS
    issueA(s);
    writeB();
    __syncthreads();                 // drains GLL (vmcnt) + ds writes
    if (s + 1 < 144) loadFeat(s + 1);   // in flight over compute
    short8 fa[3][4];
    #pragma unroll
    for (int pl = 0; pl < 3; ++pl)
      #pragma unroll
      for (int f = 0; f < 4; ++f)
        fa[pl][f] = rdFrag(smem + pl * 8192, wch0 + f * 16 + lrow);
    #pragma unroll
    for (int jb = 0; jb < 3; ++jb) {
      short8 fb[4];
      #pragma unroll
      for (int f = 0; f < 4; ++f)
        fb[f] = rdFrag(smem + 24576 + jb * 8192, wpix0 + f * 16 + lrow);
      const int na = 3 - jb;         // plane-sum <= 2
      #pragma unroll
      for (int ap = 0; ap < 3; ++ap) {
        if (ap < na) {
          #pragma unroll
          for (int i = 0; i < 4; ++i)
            #pragma unroll
            for (int j = 0; j < 4; ++j)
              acc[i][j] = __builtin_amdgcn_mfma_f32_16x16x32_bf16(
                  fa[ap][i], fb[j], acc[i][j], 0, 0, 0);
        }
      }
    }
  }

  const int chb = ct * 128 + wch0 + lg * 4;
  #pragma unroll
  for (int i = 0; i < 4; ++i) {
    int ch = chb + i * 16;
    float4 bias = *(const float4*)&b1[ch];
    #pragma unroll
    for (int j = 0; j < 4; ++j) {
      int pix = n0 + wpix0 + j * 16 + lrow;
      if (pix < 2500) {
        float4 o;
        o.x = fmaxf(acc[i][j][0] + bias.x, 0.f);
        o.y = fmaxf(acc[i][j][1] + bias.y, 0.f);
        o.z = fmaxf(acc[i][j][2] + bias.z, 0.f);
        o.w = fmaxf(acc[i][j][3] + bias.w, 0.f);
        *(float4*)&conv1[(size_t)(b * 2500 + pix) * 512 + ch] = o;
      }
    }
  }
}

// ------------------------------------------------------------------
// Guard ref: fp32 partial conv for 2 pixel slices (b=0), K split by
// tap. psum[slice2][ocb8][tap9][128pix][64oc].
// ------------------------------------------------------------------
__global__ __launch_bounds__(256) void refslice_kernel(
    const float* __restrict__ feat, const float* __restrict__ W1,
    float* __restrict__ psum) {
  __shared__ float As[32][64];
  __shared__ float Bs[32][132];
  const int tid = threadIdx.x;
  const int slice = blockIdx.x, ob = blockIdx.y, tap = blockIdx.z;
  const int pixbase = slice ? 2432 : 0;
  const int ocb = ob * 64;
  const int dy = tap / 3 - 1, dx = tap % 3 - 1;
  const int spix = tid & 127, kh = tid >> 7;
  int p = pixbase + spix;
  int y = p / 50, x = p - y * 50;
  int iy = y + dy, ix = x + dx;
  bool ok = (p < 2500) && ((unsigned)iy < 50u) && ((unsigned)ix < 50u);
  const int aoc = tid & 63, akk0 = (tid >> 6) * 8;
  const int tn = tid & 31, tm = tid >> 5;
  float acc[8][4];
  #pragma unroll
  for (int i = 0; i < 8; ++i)
    #pragma unroll
    for (int j = 0; j < 4; ++j) acc[i][j] = 0.f;
  for (int cb = 0; cb < 512; cb += 32) {
    #pragma unroll
    for (int e = 0; e < 8; ++e)
      As[akk0 + e][aoc] = W1[((size_t)(ocb + aoc) * 512 + cb + akk0 + e) * 9 + tap];
    #pragma unroll
    for (int i = 0; i < 16; ++i) {
      int kk = kh * 16 + i;
      Bs[kk][spix] = ok ? feat[(size_t)(cb + kk) * 2500 + iy * 50 + ix] : 0.f;
    }
    __syncthreads();
    for (int kk = 0; kk < 32; ++kk) {
      float a[8], bb[4];
      *(float4*)&a[0] = *(const float4*)&As[kk][tm * 8];
      *(float4*)&a[4] = *(const float4*)&As[kk][tm * 8 + 4];
      *(float4*)&bb[0] = *(const float4*)&Bs[kk][tn * 4];
      #pragma unroll
      for (int i = 0; i < 8; ++i)
        #pragma unroll
        for (int j = 0; j < 4; ++j)
          acc[i][j] = fmaf(a[i], bb[j], acc[i][j]);
    }
    __syncthreads();
  }
  float* dst = psum + ((size_t)(slice * 8 + ob) * 9 + tap) * 8192;
  #pragma unroll
  for (int j = 0; j < 4; ++j)
    #pragma unroll
    for (int i = 0; i < 8; ++i)
      dst[(tn * 4 + j) * 64 + tm * 8 + i] = acc[i][j];
}

// ------------------------------------------------------------------
// Guard compare: max|ref - conv1| over the slices -> maxd (atomicMax).
// ------------------------------------------------------------------
__global__ __launch_bounds__(256) void guardcmp_kernel(
    const float* __restrict__ psum, const float* __restrict__ b1,
    const float* __restrict__ conv1, unsigned* __restrict__ maxd) {
  int gid = blockIdx.x * 256 + threadIdx.x;      // 512*256 = 131072 exact
  int slice = gid >> 16;
  int rem = gid & 65535;
  int plocal = rem >> 9;
  int oc = rem & 511;
  float ref = b1[oc];
  #pragma unroll
  for (int tap = 0; tap < 9; ++tap)
    ref += psum[((size_t)(slice * 8 + (oc >> 6)) * 9 + tap) * 8192
                + plocal * 64 + (oc & 63)];
  ref = fmaxf(ref, 0.f);
  int pg = slice ? 2432 + plocal : plocal;
  if (pg < 2500) {
    float d = fabsf(ref - conv1[(size_t)pg * 512 + oc]);
    atomicMax(maxd, __float_as_uint(d));
  }
}

// ------------------------------------------------------------------
// fp32 conv (round-2, known-good). Runs as predicated fallback
// (early-exits when guard says MFMA matched) or as primary (force=1).
// ------------------------------------------------------------------
__global__ __launch_bounds__(256) void conv3x3_kernel(
    const float* __restrict__ feat, const float* __restrict__ W1,
    const float* __restrict__ b1, float* __restrict__ out,
    const unsigned* __restrict__ maxd, int force) {
  if (!force && __uint_as_float(*maxd) <= GUARD_TOL) return;
  __shared__ float As[36][132];
  __shared__ float Bs[36][128];
  const int tid = threadIdx.x;
  const int b  = blockIdx.z;
  const int m0 = blockIdx.y * 128;
  const int n0 = blockIdx.x * 128;
  const int tn = tid & 15, tm = tid >> 4;
  const int lm = tid & 127;
  const int kh = tid >> 7;
  const int ng = n0 + lm;
  const int yy = ng / 50;
  const int xx = ng - yy * 50;
  const bool npix_ok = (ng < 2500);
  const float* featb = feat + b * (512 * 2500);
  const float* arow  = W1 + (m0 + lm) * 4608;
  float acc[8][8];
  #pragma unroll
  for (int i = 0; i < 8; ++i)
    #pragma unroll
    for (int j = 0; j < 8; ++j) acc[i][j] = 0.f;
  for (int kc = 0; kc < 4608; kc += 36) {
    #pragma unroll
    for (int i = 0; i < 18; ++i) { int k = i * 2 + kh; As[k][lm] = arow[kc + k]; }
    #pragma unroll
    for (int i = 0; i < 18; ++i) {
      int k = i * 2 + kh;
      int kg = kc + k;
      int cin = kg / 9;
      int off = kg - cin * 9;
      int dy = off / 3;
      int dx = off - dy * 3;
      int iy = yy + dy - 1, ix = xx + dx - 1;
      float v = 0.f;
      if (npix_ok && (unsigned)iy < 50u && (unsigned)ix < 50u)
        v = featb[cin * 2500 + iy * 50 + ix];
      Bs[k][lm] = v;
    }
    __syncthreads();
    for (int k = 0; k < 36; ++k) {
      float a[8], bb[8];
      *(float4*)&a[0]  = *(const float4*)&As[k][tm * 8];
      *(float4*)&a[4]  = *(const float4*)&As[k][tm * 8 + 4];
      *(float4*)&bb[0] = *(const float4*)&Bs[k][tn * 8];
      *(float4*)&bb[4] = *(const float4*)&Bs[k][tn * 8 + 4];
      #pragma unroll
      for (int i = 0; i < 8; ++i)
        #pragma unroll
        for (int j = 0; j < 8; ++j)
          acc[i][j] = fmaf(a[i], bb[j], acc[i][j]);
    }
    __syncthreads();
  }
  float bias[8];
  *(float4*)&bias[0] = *(const float4*)&b1[m0 + tm * 8];
  *(float4*)&bias[4] = *(const float4*)&b1[m0 + tm * 8 + 4];
  for (int j = 0; j < 8; ++j) {
    int n = n0 + tn * 8 + j;
    if (n >= 2500) break;
    float* op = out + (size_t)(b * 2500 + n) * 512 + m0 + tm * 8;
    float4 v0, v1;
    v0.x = fmaxf(acc[0][j] + bias[0], 0.f); v0.y = fmaxf(acc[1][j] + bias[1], 0.f);
    v0.z = fmaxf(acc[2][j] + bias[2], 0.f); v0.w = fmaxf(acc[3][j] + bias[3], 0.f);
    v1.x = fmaxf(acc[4][j] + bias[4], 0.f); v1.y = fmaxf(acc[5][j] + bias[5], 0.f);
    v1.z = fmaxf(acc[6][j] + bias[6], 0.f); v1.w = fmaxf(acc[7][j] + bias[7], 0.f);
    *(float4*)op       = v0;
    *(float4*)(op + 4) = v1;
  }
}

// ------------------------------------------------------------------
// Heads (unchanged, verified)
// ------------------------------------------------------------------
__global__ __launch_bounds__(256) void heads_kernel(
    const float* __restrict__ conv1,
    const float* __restrict__ Wreg, const float* __restrict__ breg,
    const float* __restrict__ Wcls, const float* __restrict__ bcls,
    float* __restrict__ boxes, float* __restrict__ scores) {
  __shared__ float v[4][512];
  __shared__ float o54[4][56];
  const int tid = threadIdx.x;
  const int w = tid >> 6, lane = tid & 63;
  const int pix = blockIdx.x * 4 + w;
  const int b = pix / 2500;
  const int n = pix - b * 2500;
  const int y = n / 50, x = n - y * 50;
  const float* src = conv1 + (size_t)pix * 512;
  *(float4*)&v[w][lane * 8]     = *(const float4*)&src[lane * 8];
  *(float4*)&v[w][lane * 8 + 4] = *(const float4*)&src[lane * 8 + 4];
  __syncthreads();
  if (lane < 54) {
    const float* wrow = (lane < 36) ? (Wreg + lane * 512) : (Wcls + (lane - 36) * 512);
    float s0 = 0.f, s1 = 0.f, s2 = 0.f, s3 = 0.f;
    for (int c = 0; c < 512; c += 4) {
      float4 wv = *(const float4*)&wrow[c];
      float4 vv = *(const float4*)&v[w][c];
      s0 = fmaf(vv.x, wv.x, s0);
      s1 = fmaf(vv.y, wv.y, s1);
      s2 = fmaf(vv.z, wv.z, s2);
      s3 = fmaf(vv.w, wv.w, s3);
    }
    o54[w][lane] = (s0 + s1) + (s2 + s3) + (lane < 36 ? breg[lane] : bcls[lane - 36]);
  }
  __syncthreads();
  if (lane < 9) {
    const int a = lane;
    float d0 = o54[w][a * 4 + 0], d1 = o54[w][a * 4 + 1];
    float d2 = o54[w][a * 4 + 2], d3 = o54[w][a * 4 + 3];
    float sc0 = o54[w][36 + a * 2], sc1 = o54[w][36 + a * 2 + 1];
    float mx = fmaxf(sc0, sc1);
    float e0 = expf(sc0 - mx), e1 = expf(sc1 - mx);
    float fg = e1 / (e0 + e1);
    const int ri = a / 3;
    const int si = a - ri * 3;
    float sv = (si == 0) ? 8.f : (si == 1 ? 16.f : 32.f);
    float sqr_r  = (ri == 0) ? 0.70710678f : (ri == 1 ? 1.f : 1.41421356f);
    float sqr_ir = (ri == 0) ? 1.41421356f : (ri == 1 ? 1.f : 0.70710678f);
    float hh = 16.f * sv * sqr_r;
    float ww = 16.f * sv * sqr_ir;
    float acy = 16.f * (float)(y + 1) - 25.f;
    float acx = 16.f * (float)(x + 1) - 25.f;
    float ay1 = acy - 0.5f * hh, ay2 = acy + 0.5f * hh;
    float ax1 = acx - 0.5f * ww, ax2 = acx + 0.5f * ww;
    float ah = ay2 - ay1, aw = ax2 - ax1;
    float cy0 = ay1 + 0.5f * ah, cx0 = ax1 + 0.5f * aw;
    float cy = d0 * ah + cy0, cx = d1 * aw + cx0;
    float bh = expf(d2) * ah, bw = expf(d3) * aw;
    float y1 = cy - 0.5f * bh, x1 = cx - 0.5f * bw;
    float y2 = cy + 0.5f * bh, x2 = cx + 0.5f * bw;
    y1 = fminf(fmaxf(y1, 0.f), 800.f); y2 = fminf(fmaxf(y2, 0.f), 800.f);
    x1 = fminf(fmaxf(x1, 0.f), 800.f); x2 = fminf(fmaxf(x2, 0.f), 800.f);
    bool ok = ((y2 - y1) >= 16.f) && ((x2 - x1) >= 16.f);
    int gi = b * 22500 + n * 9 + a;
    ((float4*)boxes)[gi] = make_float4(y1, x1, y2, x2);
    scores[gi] = (ok && fg == fg) ? fg : NEGV;
  }
}

// ------------------------------------------------------------------
// Top-6000 radix select (unchanged, verified)
// ------------------------------------------------------------------
__global__ __launch_bounds__(256) void topk_kernel(
    const float* __restrict__ scores, const float* __restrict__ boxes,
    float* __restrict__ tsc, float* __restrict__ tbx, int* __restrict__ tidx) {
  const int b = blockIdx.x, tid = threadIdx.x;
  __shared__ unsigned hist[256];
  __shared__ unsigned long long sh_pref;
  __shared__ unsigned sh_rem, sh_cnt;
  const float* sc = scores + b * 22500;
  if (tid == 0) { sh_pref = 0ull; sh_rem = 6000u; }
  __syncthreads();
  for (int pass = 0; pass < 6; ++pass) {
    const int shift = 40 - pass * 8;
    hist[tid] = 0u;
    __syncthreads();
    const unsigned long long pref = sh_pref;
    for (int j = tid; j < 22500; j += 256) {
      unsigned long long key = key48(sc[j], j);
      if ((key >> (shift + 8)) == pref)
        atomicAdd(&hist[(unsigned)(key >> shift) & 255u], 1u);
    }
    __syncthreads();
    if (tid == 0) {
      unsigned rem = sh_rem;
      unsigned c = 0; int sel = 0;
      for (int bin = 255; bin >= 0; --bin) {
        unsigned nc = c + hist[bin];
        if (nc >= rem) { sel = bin; break; }
        c = nc;
      }
      sh_rem = rem - c;
      sh_pref = (sh_pref << 8) | (unsigned long long)sel;
    }
    __syncthreads();
  }
  const unsigned long long T = sh_pref;
  if (tid == 0) sh_cnt = 0u;
  __syncthreads();
  const float4* bx4 = (const float4*)boxes;
  float4* tb4 = (float4*)tbx;
  for (int j = tid; j < 22500; j += 256) {
    unsigned long long key = key48(sc[j], j);
    if (key >= T) {
      unsigned slot = atomicAdd(&sh_cnt, 1u);
      if (slot < 6000u) {
        tsc[b * 6000 + slot] = sc[j];
        tidx[b * 6000 + slot] = j;
        tb4[b * 6000 + slot] = bx4[b * 22500 + j];
      }
    }
  }
}

// ------------------------------------------------------------------
// Greedy NMS (unchanged, verified)
// ------------------------------------------------------------------
__global__ __launch_bounds__(512) void nms_kernel(
    const float* __restrict__ tsc, const float* __restrict__ tbx,
    const int* __restrict__ tidx, float* __restrict__ out) {
  const int b = blockIdx.x, tid = threadIdx.x;
  __shared__ unsigned long long kk[6000];
  __shared__ unsigned long long wk[8];
  __shared__ int wslot[8];
  __shared__ float cur_s, cur_y1, cur_x1, cur_y2, cur_x2, cur_a;
  __shared__ int cur_slot;
  const float4* boxes = (const float4*)tbx + (size_t)b * 6000;
  const float* scs = tsc + b * 6000;
  const int* idxs = tidx + b * 6000;
  float4 bx[12]; float arr[12];
  #pragma unroll
  for (int i = 0; i < 12; ++i) {
    int j = tid + i * 512;
    if (j < 6000) {
      bx[i] = boxes[j];
      arr[i] = (bx[i].z - bx[i].x) * (bx[i].w - bx[i].y);
      kk[j] = key48(scs[j], idxs[j]);
    }
  }
  __syncthreads();
  unsigned long long bk = 0ull; int bs = 0;
  #pragma unroll
  for (int i = 0; i < 12; ++i) {
    int j = tid + i * 512;
    if (j < 6000) { unsigned long long k = kk[j]; if (k > bk) { bk = k; bs = j; } }
  }
  #pragma unroll
  for (int off = 32; off > 0; off >>= 1) {
    unsigned long long ok_ = __shfl_down(bk, off);
    int os = __shfl_down(bs, off);
    if (ok_ > bk) { bk = ok_; bs = os; }
  }
  if ((tid & 63) == 0) { wk[tid >> 6] = bk; wslot[tid >> 6] = bs; }
  __syncthreads();
  if (tid == 0) {
    unsigned long long v = wk[0]; int s = wslot[0];
    for (int k2 = 1; k2 < 8; ++k2)
      if (wk[k2] > v) { v = wk[k2]; s = wslot[k2]; }
    float4 bb = boxes[s];
    cur_s = unkey_score(v); cur_slot = s;
    cur_y1 = bb.x; cur_x1 = bb.y; cur_y2 = bb.z; cur_x2 = bb.w;
    cur_a = (bb.z - bb.x) * (bb.w - bb.y);
  }
  __syncthreads();
  float* rois = out;
  float* rsc  = out + 12000;
  for (int t = 0; t < 300; ++t) {
    const float cs = cur_s, cy1 = cur_y1, cx1 = cur_x1, cy2 = cur_y2, cx2 = cur_x2, ca = cur_a;
    const int ci = cur_slot;
    if (!(cs > NEGH)) {
      for (int r = t + tid; r < 300; r += 512) {
        float* rp = rois + (size_t)(b * 300 + r) * 5;
        rp[0] = 0.f; rp[1] = 0.f; rp[2] = 0.f; rp[3] = 0.f; rp[4] = 0.f;
        rsc[b * 300 + r] = 0.f;
      }
      break;
    }
    bk = 0ull; bs = 0;
    #pragma unroll
    for (int i = 0; i < 12; ++i) {
      int j = tid + i * 512;
      if (j < 6000) {
        unsigned long long k = kk[j];
        if (k != 0ull) {
          if (j == ci) { kk[j] = 0ull; k = 0ull; }
          else {
            float yy1 = fmaxf(cy1, bx[i].x), xx1 = fmaxf(cx1, bx[i].y);
            float yy2 = fminf(cy2, bx[i].z), xx2 = fminf(cx2, bx[i].w);
            float inter = fmaxf(yy2 - yy1, 0.f) * fmaxf(xx2 - xx1, 0.f);
            float iou = inter / (((ca + arr[i]) - inter) + 1e-9f);
            if (iou > 0.7f) { kk[j] = 0ull; k = 0ull; }
          }
        }
        if (k > bk) { bk = k; bs = j; }
      }
    }
    #pragma unroll
    for (int off = 32; off > 0; off >>= 1) {
      unsigned long long ok_ = __shfl_down(bk, off);
      int os = __shfl_down(bs, off);
      if (ok_ > bk) { bk = ok_; bs = os; }
    }
    if ((tid & 63) == 0) { wk[tid >> 6] = bk; wslot[tid >> 6] = bs; }
    __syncthreads();
    if (tid == 0) {
      float* rp = rois + (size_t)(b * 300 + t) * 5;
      rp[0] = (float)b; rp[1] = cy1; rp[2] = cx1; rp[3] = cy2; rp[4] = cx2;
      rsc[b * 300 + t] = cs;
      unsigned long long v = wk[0]; int s = wslot[0];
      for (int k2 = 1; k2 < 8; ++k2)
        if (wk[k2] > v) { v = wk[k2]; s = wslot[k2]; }
      float4 bb = boxes[s];
      cur_s = unkey_score(v); cur_slot = s;
      cur_y1 = bb.x; cur_x1 = bb.y; cur_y2 = bb.z; cur_x2 = bb.w;
      cur_a = (bb.z - bb.x) * (bb.w - bb.y);
    }
    __syncthreads();
  }
}

// ------------------------------------------------------------------
extern "C" void kernel_launch(void* const* d_in, const int* in_sizes, int n_in,
                              void* d_out, int out_size, void* d_ws, size_t ws_size,
                              hipStream_t stream) {
  const float* feat = (const float*)d_in[0];
  const float* W1   = (const float*)d_in[1];
  const float* b1   = (const float*)d_in[2];
  const float* Wreg = (const float*)d_in[3];
  const float* breg = (const float*)d_in[4];
  const float* Wcls = (const float*)d_in[5];
  const float* bcls = (const float*)d_in[6];
  float* out = (float*)d_out;
  float* ws  = (float*)d_ws;

  // ws layout (floats):
  //  W1pack 3,538,944 | conv1 10,240,000 | psum 1,179,648 | maxd 64
  //  boxes 720,000 | scores 180,000 | tbx 192,000 | tsc 48,000 | tidx 48,000
  //  total 16,146,656 f = 64,586,624 B  (ws proven >= 94.7 MB in round 3)
  const size_t NEED = 64586624ull;
  if (ws_size >= NEED) {
    unsigned* W1pack = (unsigned*)ws;
    float* conv1  = ws + 3538944;
    float* psum   = ws + 13778944;
    unsigned* maxd = (unsigned*)(ws + 14958592);
    float* boxes  = ws + 14958656;
    float* scores = ws + 15678656;
    float* tbx    = ws + 15858656;
    float* tsc    = ws + 16050656;
    int*   tidx   = (int*)(ws + 16098656);

    w1pack_kernel<<<13824, 256, 0, stream>>>(W1, W1pack, maxd);
    conv_mfma_kernel<<<dim3(20, 4, 8), 256, 0, stream>>>(feat, (const char*)W1pack, b1, conv1);
    refslice_kernel<<<dim3(2, 8, 9), 256, 0, stream>>>(feat, W1, psum);
    guardcmp_kernel<<<512, 256, 0, stream>>>(psum, b1, conv1, maxd);
    conv3x3_kernel<<<dim3(20, 4, 8), 256, 0, stream>>>(feat, W1, b1, conv1, maxd, 0);
    heads_kernel<<<5000, 256, 0, stream>>>(conv1, Wreg, breg, Wcls, bcls, boxes, scores);
    topk_kernel<<<8, 256, 0, stream>>>(scores, boxes, tsc, tbx, tidx);
    nms_kernel<<<8, 512, 0, stream>>>(tsc, tbx, tidx, out);
  } else if (ws_size >= 45712000ull) {
    float* conv1  = ws;
    float* boxes  = ws + 10240000;
    float* scores = ws + 10960000;
    float* tbx    = ws + 11140000;
    float* tsc    = ws + 11332000;
    int*   tidx   = (int*)(ws + 11380000);
    unsigned* maxd = (unsigned*)(ws + 11428000);
    conv3x3_kernel<<<dim3(20, 4, 8), 256, 0, stream>>>(feat, W1, b1, conv1, maxd, 1);
    heads_kernel<<<5000, 256, 0, stream>>>(conv1, Wreg, breg, Wcls, bcls, boxes, scores);
    topk_kernel<<<8, 256, 0, stream>>>(scores, boxes, tsc, tbx, tidx);
    nms_kernel<<<8, 512, 0, stream>>>(tsc, tbx, tidx, out);
  }
}